// Round 14
// baseline (136.587 us; speedup 1.0000x reference)
//
#include <hip/hip_runtime.h>
#include <hip/hip_bf16.h>
#include <cstdint>
#include <cstddef>

typedef __bf16 bf16;
typedef __attribute__((ext_vector_type(8))) __bf16 bf16x8;
typedef __attribute__((ext_vector_type(4))) __bf16 bf16x4;
typedef __attribute__((ext_vector_type(4))) float f32x4;
typedef __attribute__((ext_vector_type(16))) float f32x16;
typedef __attribute__((ext_vector_type(4))) unsigned int u32x4;

#define MFMA16x16x32(a, b, c) __builtin_amdgcn_mfma_f32_16x16x32_bf16((a), (b), (c), 0, 0, 0)
#define MFMA32x32x16(a, b, c) __builtin_amdgcn_mfma_f32_32x32x16_bf16((a), (b), (c), 0, 0, 0)

__device__ __forceinline__ void gload16(const void* g, void* l) {
  __builtin_amdgcn_global_load_lds((const __attribute__((address_space(1))) unsigned int*)g,
                                   (__attribute__((address_space(3))) unsigned int*)l,
                                   16, 0, 0);
}

__device__ __forceinline__ unsigned packbf(float a, float b) {
  unsigned short ua = __builtin_bit_cast(unsigned short, (bf16)a);
  unsigned short ub = __builtin_bit_cast(unsigned short, (bf16)b);
  return (unsigned)ua | ((unsigned)ub << 16);
}

// raw v_exp_f32 (2^x): single VOP1; avoids the __ocml_exp2_f32 libcall.
// Verified R12/R13. x < -126 underflows to exact 0.
__device__ __forceinline__ float fexp2(float x) {
  float r;
  asm("v_exp_f32 %0, %1" : "=v"(r) : "v"(x));
  return r;
}

// ============ fused preprocessing: one dispatch, block-range dispatch ============
__global__ __launch_bounds__(256) void prep_fused(const float* __restrict__ x,
                                                  const float* __restrict__ w_c,
                                                  const float* __restrict__ w_k,
                                                  const float* __restrict__ w_v,
                                                  const float* __restrict__ w_q,
                                                  const float* __restrict__ w_o,
                                                  bf16* __restrict__ xb,
                                                  bf16* __restrict__ BTq,
                                                  bf16* __restrict__ WoutT) {
  __shared__ __align__(16) char smem[2 * 64 * 65 * 4];
  const int bi = blockIdx.x;
  const int t = threadIdx.x;

  if (bi < 4096) {  // ---- x convert ----
    int i = bi * 256 + t;
    float4 v = reinterpret_cast<const float4*>(x)[i];
    bf16x4 o;
    o[0] = (bf16)v.x; o[1] = (bf16)v.y; o[2] = (bf16)v.z; o[3] = (bf16)v.w;
    *reinterpret_cast<bf16x4*>(xb + (size_t)i * 4) = o;
    return;
  }

  if (bi < 4112) {  // ---- w_c transpose -> BTq rows 1024..1087 ----
    auto tile = (bf16(*)[72])smem;
    const int r0 = (bi - 4096) * 64;
    bf16* out = BTq + (size_t)1024 * 1024;
    {
      int rr = t >> 4;
      int cc = (t & 15) * 4;
#pragma unroll
      for (int p = 0; p < 4; ++p) {
        float4 v = *(const float4*)&w_c[(size_t)(r0 + rr + 16 * p) * 64 + cc];
        bf16x4 o;
        o[0] = (bf16)v.x; o[1] = (bf16)v.y; o[2] = (bf16)v.z; o[3] = (bf16)v.w;
        *(bf16x4*)&tile[rr + 16 * p][cc] = o;
      }
    }
    __syncthreads();
    {
      int cc = t >> 3;
      int rr = (t & 7) * 8;
#pragma unroll
      for (int p = 0; p < 2; ++p) {
        bf16x8 v;
#pragma unroll
        for (int j = 0; j < 8; ++j) v[j] = tile[rr + j][cc + 32 * p];
        *(bf16x8*)&out[(size_t)(cc + 32 * p) * 1024 + r0 + rr] = v;
      }
    }
    return;
  }

  auto Aq = (float(*)[65])smem;
  auto Ak = (float(*)[65])(smem + 64 * 65 * 4);

  if (bi < 4368) {  // ---- W_qlatT (scale folded) ----
    const int blk = bi - 4112;
    const int h = blk >> 4, dm0 = (blk & 15) * 64;
    {
      int row = t >> 2, c0 = (t & 3) * 16;
#pragma unroll
      for (int j = 0; j < 4; ++j) {
        float4 vq = *(const float4*)&w_q[(size_t)(dm0 + row) * 1024 + h * 64 + c0 + 4 * j];
        Aq[row][c0 + 4 * j + 0] = vq.x; Aq[row][c0 + 4 * j + 1] = vq.y;
        Aq[row][c0 + 4 * j + 2] = vq.z; Aq[row][c0 + 4 * j + 3] = vq.w;
        float4 vk = *(const float4*)&w_k[(size_t)row * 1024 + h * 64 + c0 + 4 * j];
        Ak[row][c0 + 4 * j + 0] = vk.x; Ak[row][c0 + 4 * j + 1] = vk.y;
        Ak[row][c0 + 4 * j + 2] = vk.z; Ak[row][c0 + 4 * j + 3] = vk.w;
      }
    }
    __syncthreads();
    const int ld0 = (t >> 4) * 4, dmq = (t & 15) * 4;
    float acc[4][4] = {};
    for (int dh = 0; dh < 64; ++dh) {
      float rk[4], rq[4];
#pragma unroll
      for (int i = 0; i < 4; ++i) rk[i] = Ak[ld0 + i][dh];
#pragma unroll
      for (int j = 0; j < 4; ++j) rq[j] = Aq[dmq + j][dh];
#pragma unroll
      for (int i = 0; i < 4; ++i)
#pragma unroll
        for (int j = 0; j < 4; ++j) acc[i][j] += rk[i] * rq[j];
    }
    const float S = 0.18033688011112042f;  // 1/sqrt(64) * log2(e)
#pragma unroll
    for (int i = 0; i < 4; ++i) {
      bf16x4 o;
#pragma unroll
      for (int j = 0; j < 4; ++j) o[j] = (bf16)(acc[i][j] * S);
      *(bf16x4*)&BTq[(size_t)(h * 64 + ld0 + i) * 1024 + dm0 + dmq] = o;
    }
    return;
  }

  {  // ---- W_outT ----
    const int blk = bi - 4368;
    const int h = blk >> 4, dn0 = (blk & 15) * 64;
    {
      int row = t >> 2, c0 = (t & 3) * 16;
#pragma unroll
      for (int j = 0; j < 4; ++j) {
        float4 vv = *(const float4*)&w_v[(size_t)row * 1024 + h * 64 + c0 + 4 * j];
        Aq[row][c0 + 4 * j + 0] = vv.x; Aq[row][c0 + 4 * j + 1] = vv.y;
        Aq[row][c0 + 4 * j + 2] = vv.z; Aq[row][c0 + 4 * j + 3] = vv.w;
        float4 vo = *(const float4*)&w_o[(size_t)(h * 64 + row) * 1024 + dn0 + c0 + 4 * j];
        Ak[row][c0 + 4 * j + 0] = vo.x; Ak[row][c0 + 4 * j + 1] = vo.y;
        Ak[row][c0 + 4 * j + 2] = vo.z; Ak[row][c0 + 4 * j + 3] = vo.w;
      }
    }
    __syncthreads();
    const int dnq = (t >> 4) * 4, lv0 = (t & 15) * 4;
    float acc[4][4] = {};
    for (int dh = 0; dh < 64; ++dh) {
      float ro[4], rv[4];
#pragma unroll
      for (int i = 0; i < 4; ++i) ro[i] = Ak[dh][dnq + i];
#pragma unroll
      for (int j = 0; j < 4; ++j) rv[j] = Aq[lv0 + j][dh];
#pragma unroll
      for (int i = 0; i < 4; ++i)
#pragma unroll
        for (int j = 0; j < 4; ++j) acc[i][j] += ro[i] * rv[j];
    }
#pragma unroll
    for (int i = 0; i < 4; ++i) {
      bf16x4 o;
#pragma unroll
      for (int j = 0; j < 4; ++j) o[j] = (bf16)acc[i][j];
      *(bf16x4*)&WoutT[(size_t)(dn0 + dnq + i) * 1024 + h * 64 + lv0] = o;
    }
  }
}

// ------------- latT from fused QL buffer, K-PERMUTED layout (R13-verified) -------------
__global__ __launch_bounds__(256) void make_latT(const bf16* __restrict__ QL,
                                                 bf16* __restrict__ latT) {
  __shared__ __align__(16) bf16 tile[64][72];
  const int r0 = blockIdx.x * 64;
  const int t = threadIdx.x;
  {
    int row = t >> 2, c0 = (t & 3) * 16;
    const bf16* src = QL + (size_t)(r0 + row) * 1088 + 1024 + c0;
    *(bf16x8*)&tile[row][c0] = *(const bf16x8*)src;
    *(bf16x8*)&tile[row][c0 + 8] = *(const bf16x8*)(src + 8);
  }
  __syncthreads();
  {
    int d = t >> 2, tc = (t & 3) * 16;
    const int g1[8] = {0, 1, 2, 3, 8, 9, 10, 11};
    const int g2[8] = {4, 5, 6, 7, 12, 13, 14, 15};
    bf16x8 v0, v1;
#pragma unroll
    for (int j = 0; j < 8; ++j) {
      v0[j] = tile[tc + g1[j]][d];
      v1[j] = tile[tc + g2[j]][d];
    }
    *(bf16x8*)&latT[(size_t)d * 4096 + r0 + tc] = v0;
    *(bf16x8*)&latT[(size_t)d * 4096 + r0 + tc + 8] = v1;
  }
}

// ---------------- bf16 MFMA GEMM: C[M,N] = A[M,K] * BT[N,K]^T ----------------
template <int BM, int BN, int WM, int WN, bool OUT_F32>
__global__ __launch_bounds__(256) void gemm_bf16(const bf16* __restrict__ A,
                                                 const bf16* __restrict__ BT,
                                                 void* __restrict__ C,
                                                 int N, int K) {
  constexpr int BK = 32;
  constexpr int TM = (BM / WM) / 16;
  constexpr int TN = (BN / WN) / 16;
  __shared__ __align__(16) bf16 As[BM * BK];
  __shared__ __align__(16) bf16 Bs[BN * BK];
  const int tid = threadIdx.x;
  const int lane = tid & 63;
  const int wid = tid >> 6;
  const int wm = wid / WN;
  const int wn = wid % WN;
  const int bm = blockIdx.x * BM;
  const int bn = blockIdx.y * BN;
  const int arow = lane & 15;
  const int koff = (lane >> 4) * 8;

  f32x4 acc[TM][TN] = {};

  for (int kb = 0; kb < K; kb += BK) {
    for (int base = wid * 1024; base < BM * 64; base += 4096) {
      int off = base + lane * 16;
      int row = off >> 6;
      int col = off & 63;
      gload16((const char*)A + ((size_t)(bm + row) * K + kb) * 2 + col, (char*)As + base);
    }
    for (int base = wid * 1024; base < BN * 64; base += 4096) {
      int off = base + lane * 16;
      int row = off >> 6;
      int col = off & 63;
      gload16((const char*)BT + ((size_t)(bn + row) * K + kb) * 2 + col, (char*)Bs + base);
    }
    __syncthreads();

    bf16x8 af[TM], bfr[TN];
#pragma unroll
    for (int i = 0; i < TM; ++i)
      af[i] = *(const bf16x8*)&As[(wm * TM * 16 + i * 16 + arow) * BK + koff];
#pragma unroll
    for (int j = 0; j < TN; ++j)
      bfr[j] = *(const bf16x8*)&Bs[(wn * TN * 16 + j * 16 + arow) * BK + koff];
#pragma unroll
    for (int i = 0; i < TM; ++i)
#pragma unroll
      for (int j = 0; j < TN; ++j)
        acc[i][j] = MFMA16x16x32(af[i], bfr[j], acc[i][j]);
    __syncthreads();
  }

  const int m0 = bm + wm * TM * 16 + (lane >> 4) * 4;
  const int n0 = bn + wn * TN * 16 + (lane & 15);
#pragma unroll
  for (int i = 0; i < TM; ++i)
#pragma unroll
    for (int j = 0; j < TN; ++j)
#pragma unroll
      for (int r = 0; r < 4; ++r) {
        int m = m0 + i * 16 + r;
        int n = n0 + j * 16;
        float v = acc[i][j][r];
        if constexpr (OUT_F32)
          ((float*)C)[(size_t)m * N + n] = v;
        else
          ((bf16*)C)[(size_t)m * N + n] = (bf16)v;
      }
}

// ---------------- absorbed flash attention v11: split-K (R9 skeleton) + lean compute (R13) ----------------
// Block = 4 waves = one (pair p, bh). Each wave takes a K-QUARTER of chunk hi
// (63-p) then chunk lo (p): ~16.25 tiles/wave, EVERY block uniform 65/4 ->
// no correlated CU imbalance (R13 bug: co-resident blocks shared p, CU busy
// time ~ 64-p). 1024 blocks = 4/CU = 4 waves/SIMD. Static-shift softmax makes
// the split-K combine plain sums. Compute = R13-verbatim (fexp2, shuffle-free
// pack, k-permuted latT).
__global__ __launch_bounds__(256) void mla_attn4(const bf16* __restrict__ QL,
                                                 const bf16* __restrict__ latT,
                                                 bf16* __restrict__ out_lat) {
  __shared__ __align__(16) bf16 part[4][32][72];   // [wave][q(li)][d]
  __shared__ float pml[4][32];                     // [wave][q] partial lsum
  __shared__ __align__(16) bf16 etile[32][80];     // final O [q][d]
  const int tid = threadIdx.x, lane = tid & 63, w = tid >> 6;
  const int p = blockIdx.x & 31;
  const int bh = blockIdx.x >> 5;
  const int b = bh >> 4, h = bh & 15;
  const int li = lane & 31;
  const int hb = lane >> 5;
  const size_t boff = (size_t)b * 2048;
  const bf16* lat = QL + 1024;  // latent columns of the fused buffer

  auto loadK = [&](bf16x8 (&ka)[4], int kb) {
    const bf16* base = lat + ((size_t)(boff + kb + li)) * 1088 + hb * 8;
#pragma unroll
    for (int s = 0; s < 4; ++s) ka[s] = *(const bf16x8*)(base + 16 * s);
  };
  // contiguous 16B loads; k-permutation baked into latT (R13-verified)
  auto loadV = [&](bf16x8 (&va)[2][2], int kb) {
#pragma unroll
    for (int ldb = 0; ldb < 2; ++ldb) {
      const bf16* base = latT + (size_t)(32 * ldb + li) * 4096 + boff + kb + hb * 8;
#pragma unroll
      for (int s2 = 0; s2 < 2; ++s2) va[ldb][s2] = *(const bf16x8*)(base + 16 * s2);
    }
  };

  auto phase = [&](int cchunk) {
    const int q0 = cchunk * 32;
    const int nt = cchunk + 1;
    const int beg = (nt * w) >> 2;
    const int end = (nt * (w + 1)) >> 2;

    bf16x8 qf[4];
    {
      const bf16* qp = QL + ((size_t)(boff + q0 + li)) * 1088 + h * 64 + hb * 8;
#pragma unroll
      for (int s = 0; s < 4; ++s) qf[s] = *(const bf16x8*)(qp + 16 * s);
    }

    float lsum = 0.f;  // lane-private half-row sum
    f32x16 ot0 = {}, ot1 = {};

    auto tilecompute = [&](const bf16x8 (&ka)[4], const bf16x8 (&va)[2][2], bool domask) {
      f32x16 st = {};
      __builtin_amdgcn_s_setprio(1);
#pragma unroll
      for (int s = 0; s < 4; ++s) st = MFMA32x32x16(ka[s], qf[s], st);
      __builtin_amdgcn_s_setprio(0);
      if (domask) {  // diagonal tile: k_local > q_local
#pragma unroll
        for (int r = 0; r < 16; ++r) {
          const int krow = (r & 3) + 8 * (r >> 2) + 4 * hb;
          if (krow > li) st[r] = -30000.f;  // v_exp underflows to exactly 0
        }
      }
      float pv[16];
#pragma unroll
      for (int r = 0; r < 16; ++r) {
        pv[r] = fexp2(st[r]);  // unshifted: |s| small, f32 exp2 safe
        lsum += pv[r];
      }
      // shuffle-free P^T fragments (k-permutation aligns crow with B-frag slots)
      u32x4 w1, w2;
      w1[0] = packbf(pv[0], pv[1]);  w1[1] = packbf(pv[2], pv[3]);
      w1[2] = packbf(pv[4], pv[5]);  w1[3] = packbf(pv[6], pv[7]);
      w2[0] = packbf(pv[8], pv[9]);  w2[1] = packbf(pv[10], pv[11]);
      w2[2] = packbf(pv[12], pv[13]); w2[3] = packbf(pv[14], pv[15]);
      const bf16x8 pb1 = __builtin_bit_cast(bf16x8, w1);
      const bf16x8 pb2 = __builtin_bit_cast(bf16x8, w2);
      __builtin_amdgcn_s_setprio(1);
      ot0 = MFMA32x32x16(va[0][0], pb1, ot0);
      ot0 = MFMA32x32x16(va[0][1], pb2, ot0);
      ot1 = MFMA32x32x16(va[1][0], pb1, ot1);
      ot1 = MFMA32x32x16(va[1][1], pb2, ot1);
      __builtin_amdgcn_s_setprio(0);
    };

    if (beg < end) {
      bf16x8 kaA[4], vaA[2][2], kaB[4], vaB[2][2];
      loadK(kaA, beg * 32);
      loadV(vaA, beg * 32);
      int t = beg;
      while (true) {
        if (t + 1 < end) { loadK(kaB, (t + 1) * 32); loadV(vaB, (t + 1) * 32); }
        tilecompute(kaA, vaA, t == nt - 1);
        ++t;
        if (t == end) break;
        if (t + 1 < end) { loadK(kaA, (t + 1) * 32); loadV(vaA, (t + 1) * 32); }
        tilecompute(kaB, vaB, t == nt - 1);
        ++t;
        if (t == end) break;
      }
    }

    lsum += __shfl_xor(lsum, 32);  // merge the two half-row k-sets

    // ---- write partials: part[w][li][d] (bf16), pml[w][li] (f32) ----
#pragma unroll
    for (int g = 0; g < 4; ++g) {
      bf16x4 v0, v1;
#pragma unroll
      for (int j = 0; j < 4; ++j) {
        v0[j] = (bf16)ot0[4 * g + j];
        v1[j] = (bf16)ot1[4 * g + j];
      }
      *(bf16x4*)&part[w][li][8 * g + 4 * hb] = v0;
      *(bf16x4*)&part[w][li][32 + 8 * g + 4 * hb] = v1;
    }
    pml[w][li] = lsum;  // both halves write the identical value (benign)
    __syncthreads();

    // ---- combine: plain sums; wave w owns d-slice [16w, 16w+16) ----
    const float lfull = pml[0][li] + pml[1][li] + pml[2][li] + pml[3][li];
    const float inv = 1.0f / lfull;
    float od[16] = {};
#pragma unroll
    for (int w2 = 0; w2 < 4; ++w2) {
      bf16x8 u0 = *(const bf16x8*)&part[w2][li][16 * w];
      bf16x8 u1 = *(const bf16x8*)&part[w2][li][16 * w + 8];
#pragma unroll
      for (int j = 0; j < 8; ++j) {
        od[j] += (float)u0[j];
        od[8 + j] += (float)u1[j];
      }
    }
    bf16x8 e0, e1;
#pragma unroll
    for (int j = 0; j < 8; ++j) {
      e0[j] = (bf16)(od[j] * inv);
      e1[j] = (bf16)(od[8 + j] * inv);
    }
    *(bf16x8*)&etile[li][16 * w] = e0;
    *(bf16x8*)&etile[li][16 * w + 8] = e1;
    __syncthreads();

    // ---- coalesced store: wave w stores q-rows [8w, 8w+8) ----
    {
      const int row = 8 * w + (lane >> 3);
      const int c16 = (lane & 7) * 8;
      bf16x8 ev = *(const bf16x8*)&etile[row][c16];
      *(bf16x8*)(out_lat + ((size_t)(boff + q0 + row)) * 1024 + h * 64 + c16) = ev;
    }
    __syncthreads();  // part/etile reused by next phase
  };

  phase(63 - p);
  phase(p);
}

// ---------------- host launch ----------------
extern "C" void kernel_launch(void* const* d_in, const int* in_sizes, int n_in,
                              void* d_out, int out_size, void* d_ws, size_t ws_size,
                              hipStream_t stream) {
  const float* x   = (const float*)d_in[0];
  const float* w_c = (const float*)d_in[1];
  const float* w_k = (const float*)d_in[2];
  const float* w_v = (const float*)d_in[3];
  const float* w_q = (const float*)d_in[4];
  const float* w_o = (const float*)d_in[5];
  float* out = (float*)d_out;

  char* ws = (char*)d_ws;
  size_t off = 0;
  auto alloc = [&](size_t bytes) {
    char* p = ws + off;
    off += (bytes + 255) & ~(size_t)255;
    return p;
  };
  bf16* xb     = (bf16*)alloc((size_t)4096 * 1024 * 2);
  bf16* QLbuf  = (bf16*)alloc((size_t)4096 * 1088 * 2);  // q_lat | latent
  bf16* BTq    = (bf16*)alloc((size_t)1088 * 1024 * 2);  // W_qlatT ; w_c^T
  bf16* latT   = (bf16*)alloc((size_t)64 * 4096 * 2);
  bf16* outlat = (bf16*)alloc((size_t)4096 * 1024 * 2);
  bf16* WoutT  = (bf16*)alloc((size_t)1024 * 1024 * 2);

  // 1) all preprocessing in one dispatch
  prep_fused<<<4624, 256, 0, stream>>>(x, w_c, w_k, w_v, w_q, w_o, xb, BTq, WoutT);

  // 2) fused [q_lat | latent] = xb @ [W_qlatT ; w_c^T]^T : [4096][1088]
  gemm_bf16<128, 64, 2, 2, false><<<dim3(32, 17), 256, 0, stream>>>(
      xb, BTq, QLbuf, 1088, 1024);

  // 3) latT [64][4096] (k-permuted) from QLbuf latent columns
  make_latT<<<64, 256, 0, stream>>>(QLbuf, latT);

  // 4) attention: 1024 blocks (pair x bh), 4 K-split waves per block
  mla_attn4<<<1024, 256, 0, stream>>>(QLbuf, latT, outlat);

  // 5) out = out_lat @ W_outT (fp32)
  gemm_bf16<64, 128, 1, 4, true><<<dim3(64, 8), 256, 0, stream>>>(
      outlat, WoutT, (void*)out, 1024, 1024);

  (void)in_sizes; (void)n_in; (void)out_size; (void)ws_size;
}

// Round 15
// 124.341 us; speedup vs baseline: 1.0985x; 1.0985x over previous
//
#include <hip/hip_runtime.h>
#include <hip/hip_bf16.h>
#include <cstdint>
#include <cstddef>

typedef __bf16 bf16;
typedef __attribute__((ext_vector_type(8))) __bf16 bf16x8;
typedef __attribute__((ext_vector_type(4))) __bf16 bf16x4;
typedef __attribute__((ext_vector_type(4))) float f32x4;
typedef __attribute__((ext_vector_type(16))) float f32x16;
typedef __attribute__((ext_vector_type(4))) unsigned int u32x4;

#define MFMA16x16x32(a, b, c) __builtin_amdgcn_mfma_f32_16x16x32_bf16((a), (b), (c), 0, 0, 0)
#define MFMA32x32x16(a, b, c) __builtin_amdgcn_mfma_f32_32x32x16_bf16((a), (b), (c), 0, 0, 0)

__device__ __forceinline__ void gload16(const void* g, void* l) {
  __builtin_amdgcn_global_load_lds((const __attribute__((address_space(1))) unsigned int*)g,
                                   (__attribute__((address_space(3))) unsigned int*)l,
                                   16, 0, 0);
}

__device__ __forceinline__ unsigned packbf(float a, float b) {
  unsigned short ua = __builtin_bit_cast(unsigned short, (bf16)a);
  unsigned short ub = __builtin_bit_cast(unsigned short, (bf16)b);
  return (unsigned)ua | ((unsigned)ub << 16);
}

// raw v_exp_f32 (2^x): single VOP1 (verified R12/R13). x < -126 -> exact 0.
__device__ __forceinline__ float fexp2(float x) {
  float r;
  asm("v_exp_f32 %0, %1" : "=v"(r) : "v"(x));
  return r;
}

// ============ fused preprocessing: one dispatch, block-range dispatch ============
__global__ __launch_bounds__(256) void prep_fused(const float* __restrict__ x,
                                                  const float* __restrict__ w_c,
                                                  const float* __restrict__ w_k,
                                                  const float* __restrict__ w_v,
                                                  const float* __restrict__ w_q,
                                                  const float* __restrict__ w_o,
                                                  bf16* __restrict__ xb,
                                                  bf16* __restrict__ BTq,
                                                  bf16* __restrict__ WoutT) {
  __shared__ __align__(16) char smem[2 * 64 * 65 * 4];
  const int bi = blockIdx.x;
  const int t = threadIdx.x;

  if (bi < 4096) {  // ---- x convert ----
    int i = bi * 256 + t;
    float4 v = reinterpret_cast<const float4*>(x)[i];
    bf16x4 o;
    o[0] = (bf16)v.x; o[1] = (bf16)v.y; o[2] = (bf16)v.z; o[3] = (bf16)v.w;
    *reinterpret_cast<bf16x4*>(xb + (size_t)i * 4) = o;
    return;
  }

  if (bi < 4112) {  // ---- w_c transpose -> BTq rows 1024..1087 ----
    auto tile = (bf16(*)[72])smem;
    const int r0 = (bi - 4096) * 64;
    bf16* out = BTq + (size_t)1024 * 1024;
    {
      int rr = t >> 4;
      int cc = (t & 15) * 4;
#pragma unroll
      for (int p = 0; p < 4; ++p) {
        float4 v = *(const float4*)&w_c[(size_t)(r0 + rr + 16 * p) * 64 + cc];
        bf16x4 o;
        o[0] = (bf16)v.x; o[1] = (bf16)v.y; o[2] = (bf16)v.z; o[3] = (bf16)v.w;
        *(bf16x4*)&tile[rr + 16 * p][cc] = o;
      }
    }
    __syncthreads();
    {
      int cc = t >> 3;
      int rr = (t & 7) * 8;
#pragma unroll
      for (int p = 0; p < 2; ++p) {
        bf16x8 v;
#pragma unroll
        for (int j = 0; j < 8; ++j) v[j] = tile[rr + j][cc + 32 * p];
        *(bf16x8*)&out[(size_t)(cc + 32 * p) * 1024 + r0 + rr] = v;
      }
    }
    return;
  }

  auto Aq = (float(*)[65])smem;
  auto Ak = (float(*)[65])(smem + 64 * 65 * 4);

  if (bi < 4368) {  // ---- W_qlatT (scale folded) ----
    const int blk = bi - 4112;
    const int h = blk >> 4, dm0 = (blk & 15) * 64;
    {
      int row = t >> 2, c0 = (t & 3) * 16;
#pragma unroll
      for (int j = 0; j < 4; ++j) {
        float4 vq = *(const float4*)&w_q[(size_t)(dm0 + row) * 1024 + h * 64 + c0 + 4 * j];
        Aq[row][c0 + 4 * j + 0] = vq.x; Aq[row][c0 + 4 * j + 1] = vq.y;
        Aq[row][c0 + 4 * j + 2] = vq.z; Aq[row][c0 + 4 * j + 3] = vq.w;
        float4 vk = *(const float4*)&w_k[(size_t)row * 1024 + h * 64 + c0 + 4 * j];
        Ak[row][c0 + 4 * j + 0] = vk.x; Ak[row][c0 + 4 * j + 1] = vk.y;
        Ak[row][c0 + 4 * j + 2] = vk.z; Ak[row][c0 + 4 * j + 3] = vk.w;
      }
    }
    __syncthreads();
    const int ld0 = (t >> 4) * 4, dmq = (t & 15) * 4;
    float acc[4][4] = {};
    for (int dh = 0; dh < 64; ++dh) {
      float rk[4], rq[4];
#pragma unroll
      for (int i = 0; i < 4; ++i) rk[i] = Ak[ld0 + i][dh];
#pragma unroll
      for (int j = 0; j < 4; ++j) rq[j] = Aq[dmq + j][dh];
#pragma unroll
      for (int i = 0; i < 4; ++i)
#pragma unroll
        for (int j = 0; j < 4; ++j) acc[i][j] += rk[i] * rq[j];
    }
    const float S = 0.18033688011112042f;  // 1/sqrt(64) * log2(e)
#pragma unroll
    for (int i = 0; i < 4; ++i) {
      bf16x4 o;
#pragma unroll
      for (int j = 0; j < 4; ++j) o[j] = (bf16)(acc[i][j] * S);
      *(bf16x4*)&BTq[(size_t)(h * 64 + ld0 + i) * 1024 + dm0 + dmq] = o;
    }
    return;
  }

  {  // ---- W_outT ----
    const int blk = bi - 4368;
    const int h = blk >> 4, dn0 = (blk & 15) * 64;
    {
      int row = t >> 2, c0 = (t & 3) * 16;
#pragma unroll
      for (int j = 0; j < 4; ++j) {
        float4 vv = *(const float4*)&w_v[(size_t)row * 1024 + h * 64 + c0 + 4 * j];
        Aq[row][c0 + 4 * j + 0] = vv.x; Aq[row][c0 + 4 * j + 1] = vv.y;
        Aq[row][c0 + 4 * j + 2] = vv.z; Aq[row][c0 + 4 * j + 3] = vv.w;
        float4 vo = *(const float4*)&w_o[(size_t)(h * 64 + row) * 1024 + dn0 + c0 + 4 * j];
        Ak[row][c0 + 4 * j + 0] = vo.x; Ak[row][c0 + 4 * j + 1] = vo.y;
        Ak[row][c0 + 4 * j + 2] = vo.z; Ak[row][c0 + 4 * j + 3] = vo.w;
      }
    }
    __syncthreads();
    const int dnq = (t >> 4) * 4, lv0 = (t & 15) * 4;
    float acc[4][4] = {};
    for (int dh = 0; dh < 64; ++dh) {
      float ro[4], rv[4];
#pragma unroll
      for (int i = 0; i < 4; ++i) ro[i] = Ak[dh][dnq + i];
#pragma unroll
      for (int j = 0; j < 4; ++j) rv[j] = Aq[lv0 + j][dh];
#pragma unroll
      for (int i = 0; i < 4; ++i)
#pragma unroll
        for (int j = 0; j < 4; ++j) acc[i][j] += ro[i] * rv[j];
    }
#pragma unroll
    for (int i = 0; i < 4; ++i) {
      bf16x4 o;
#pragma unroll
      for (int j = 0; j < 4; ++j) o[j] = (bf16)acc[i][j];
      *(bf16x4*)&WoutT[(size_t)(dn0 + dnq + i) * 1024 + h * 64 + lv0] = o;
    }
  }
}

// ------------- latT from fused QL buffer, K-PERMUTED layout (R13-verified) -------------
__global__ __launch_bounds__(256) void make_latT(const bf16* __restrict__ QL,
                                                 bf16* __restrict__ latT) {
  __shared__ __align__(16) bf16 tile[64][72];
  const int r0 = blockIdx.x * 64;
  const int t = threadIdx.x;
  {
    int row = t >> 2, c0 = (t & 3) * 16;
    const bf16* src = QL + (size_t)(r0 + row) * 1088 + 1024 + c0;
    *(bf16x8*)&tile[row][c0] = *(const bf16x8*)src;
    *(bf16x8*)&tile[row][c0 + 8] = *(const bf16x8*)(src + 8);
  }
  __syncthreads();
  {
    int d = t >> 2, tc = (t & 3) * 16;
    const int g1[8] = {0, 1, 2, 3, 8, 9, 10, 11};
    const int g2[8] = {4, 5, 6, 7, 12, 13, 14, 15};
    bf16x8 v0, v1;
#pragma unroll
    for (int j = 0; j < 8; ++j) {
      v0[j] = tile[tc + g1[j]][d];
      v1[j] = tile[tc + g2[j]][d];
    }
    *(bf16x8*)&latT[(size_t)d * 4096 + r0 + tc] = v0;
    *(bf16x8*)&latT[(size_t)d * 4096 + r0 + tc + 8] = v1;
  }
}

// ---------------- bf16 MFMA GEMM: C[M,N] = A[M,K] * BT[N,K]^T ----------------
template <int BM, int BN, int WM, int WN, bool OUT_F32>
__global__ __launch_bounds__(256) void gemm_bf16(const bf16* __restrict__ A,
                                                 const bf16* __restrict__ BT,
                                                 void* __restrict__ C,
                                                 int N, int K) {
  constexpr int BK = 32;
  constexpr int TM = (BM / WM) / 16;
  constexpr int TN = (BN / WN) / 16;
  __shared__ __align__(16) bf16 As[BM * BK];
  __shared__ __align__(16) bf16 Bs[BN * BK];
  const int tid = threadIdx.x;
  const int lane = tid & 63;
  const int wid = tid >> 6;
  const int wm = wid / WN;
  const int wn = wid % WN;
  const int bm = blockIdx.x * BM;
  const int bn = blockIdx.y * BN;
  const int arow = lane & 15;
  const int koff = (lane >> 4) * 8;

  f32x4 acc[TM][TN] = {};

  for (int kb = 0; kb < K; kb += BK) {
    for (int base = wid * 1024; base < BM * 64; base += 4096) {
      int off = base + lane * 16;
      int row = off >> 6;
      int col = off & 63;
      gload16((const char*)A + ((size_t)(bm + row) * K + kb) * 2 + col, (char*)As + base);
    }
    for (int base = wid * 1024; base < BN * 64; base += 4096) {
      int off = base + lane * 16;
      int row = off >> 6;
      int col = off & 63;
      gload16((const char*)BT + ((size_t)(bn + row) * K + kb) * 2 + col, (char*)Bs + base);
    }
    __syncthreads();

    bf16x8 af[TM], bfr[TN];
#pragma unroll
    for (int i = 0; i < TM; ++i)
      af[i] = *(const bf16x8*)&As[(wm * TM * 16 + i * 16 + arow) * BK + koff];
#pragma unroll
    for (int j = 0; j < TN; ++j)
      bfr[j] = *(const bf16x8*)&Bs[(wn * TN * 16 + j * 16 + arow) * BK + koff];
#pragma unroll
    for (int i = 0; i < TM; ++i)
#pragma unroll
      for (int j = 0; j < TN; ++j)
        acc[i][j] = MFMA16x16x32(af[i], bfr[j], acc[i][j]);
    __syncthreads();
  }

  const int m0 = bm + wm * TM * 16 + (lane >> 4) * 4;
  const int n0 = bn + wn * TN * 16 + (lane & 15);
#pragma unroll
  for (int i = 0; i < TM; ++i)
#pragma unroll
    for (int j = 0; j < TN; ++j)
#pragma unroll
      for (int r = 0; r < 4; ++r) {
        int m = m0 + i * 16 + r;
        int n = n0 + j * 16;
        float v = acc[i][j][r];
        if constexpr (OUT_F32)
          ((float*)C)[(size_t)m * N + n] = v;
        else
          ((bf16*)C)[(size_t)m * N + n] = (bf16)v;
      }
}

// ---------------- absorbed flash attention v12: LDS-shared K/V across 4 heads ----------------
// Block = (chunk c, b, head-group of 4). 4 waves, one head each, iterate the SAME
// K/V tiles: staged cooperatively via global_load_lds (2 gload16/thread/tile),
// double-buffered, R2-verified sync skeleton {stage -> vmcnt(2) -> s_barrier ->
// compute -> lgkmcnt -> s_barrier}. 4x less L2 traffic; load latency hides under
// compute. Complementary scheduling: blocks i and i+256 get chunks 63-c and c
// (uniform 65 tiles/CU). Compute = R13-verbatim (fexp2, shuffle-free pack,
// k-permuted latT). LDS swizzle both-sides (rule #21): linear dest, inverse-
// swizzled global source, swizzled ds_read.
__global__ __launch_bounds__(256) void mla_attn5(const bf16* __restrict__ QL,
                                                 const bf16* __restrict__ latT,
                                                 bf16* __restrict__ out_lat) {
  __shared__ __align__(16) bf16 Kst[2][2048];      // [buf][32 tok][128B rows], swizzled
  __shared__ __align__(16) bf16 Vst[2][2048];      // [buf][32 srows][128B], 2 d-rows/srow, swizzled
  __shared__ __align__(16) bf16 etile[4][32][72];  // per-wave output transpose
  const int tid = threadIdx.x, lane = tid & 63, w = tid >> 6;
  const int c_raw = blockIdx.x & 63;
  const int rest = (int)(blockIdx.x >> 6);         // 0..7
  const int b = rest & 1;
  const int hg = (rest >> 1) & 3;
  const int c = (rest < 4) ? (63 - c_raw) : c_raw; // complementary pairing
  const int h = hg * 4 + w;                        // this wave's head
  const int nt = c + 1;
  const int q0 = c * 32;
  const int li = lane & 31;
  const int hb = lane >> 5;
  const size_t boff = (size_t)b * 2048;
  const bf16* lat = QL + 1024;  // latent columns of the fused buffer (row stride 1088)

  // cooperative stage of one 32-token tile: K 4KB + V 4KB, one gload16 each per thread.
  // dest is wave-uniform base + lane*16 (HW); thread tid covers 16B chunk tid.
  const int drow = tid >> 3;             // (tid*16)/128: 0..31
  const int dbyte = (tid & 7) * 16;      // byte within 128B row
  const int sbyte = dbyte ^ ((drow & 7) << 4);  // inverse swizzle (involution)
  const int vd = 2 * drow + (sbyte >> 6);       // V: packed d index
  const int vkof = (sbyte & 63) >> 1;           // V: k offset within tile (0,8,16,24)
  auto stage = [&](int buf, int kb) {
    gload16((const char*)lat + ((size_t)(boff + kb + drow) * 1088) * 2 + sbyte,
            (char*)&Kst[buf][0] + w * 1024);
    gload16((const char*)latT + ((size_t)vd * 4096 + boff + kb + vkof) * 2,
            (char*)&Vst[buf][0] + w * 1024);
  };

  bf16x8 qf[4];
  {
    const bf16* qp = QL + ((size_t)(boff + q0 + li)) * 1088 + h * 64 + hb * 8;
#pragma unroll
    for (int s = 0; s < 4; ++s) qf[s] = *(const bf16x8*)(qp + 16 * s);
  }

  float lsum = 0.f;
  f32x16 ot0 = {}, ot1 = {};

  stage(0, 0);
  for (int t = 0; t < nt; ++t) {
    const int cur = t & 1;
    if (t + 1 < nt) {
      stage(cur ^ 1, (t + 1) * 32);
      asm volatile("s_waitcnt vmcnt(2)" ::: "memory");  // tile t landed; t+1 in flight
    } else {
      asm volatile("s_waitcnt vmcnt(0)" ::: "memory");
    }
    __builtin_amdgcn_s_barrier();
    __builtin_amdgcn_sched_barrier(0);

    // ---- swizzled LDS reads ----
    bf16x8 ka[4], va[2][2];
#pragma unroll
    for (int s = 0; s < 4; ++s)
      ka[s] = *(const bf16x8*)((const char*)&Kst[cur][0] + li * 128 +
                               ((hb * 16 + 32 * s) ^ ((li & 7) << 4)));
#pragma unroll
    for (int ldb = 0; ldb < 2; ++ldb) {
      const int srow = 16 * ldb + (li >> 1);
#pragma unroll
      for (int s2 = 0; s2 < 2; ++s2) {
        const int vb = (li & 1) * 64 + hb * 16 + 32 * s2;
        va[ldb][s2] = *(const bf16x8*)((const char*)&Vst[cur][0] + srow * 128 +
                                       (vb ^ ((srow & 7) << 4)));
      }
    }

    // ---- tile compute (R13-verbatim) ----
    f32x16 st = {};
    __builtin_amdgcn_s_setprio(1);
#pragma unroll
    for (int s = 0; s < 4; ++s) st = MFMA32x32x16(ka[s], qf[s], st);
    __builtin_amdgcn_s_setprio(0);
    if (t == nt - 1) {  // diagonal tile: k_local > q_local
#pragma unroll
      for (int r = 0; r < 16; ++r) {
        const int krow = (r & 3) + 8 * (r >> 2) + 4 * hb;
        if (krow > li) st[r] = -30000.f;
      }
    }
    float pv[16];
#pragma unroll
    for (int r = 0; r < 16; ++r) {
      pv[r] = fexp2(st[r]);
      lsum += pv[r];
    }
    u32x4 w1, w2;
    w1[0] = packbf(pv[0], pv[1]);  w1[1] = packbf(pv[2], pv[3]);
    w1[2] = packbf(pv[4], pv[5]);  w1[3] = packbf(pv[6], pv[7]);
    w2[0] = packbf(pv[8], pv[9]);  w2[1] = packbf(pv[10], pv[11]);
    w2[2] = packbf(pv[12], pv[13]); w2[3] = packbf(pv[14], pv[15]);
    const bf16x8 pb1 = __builtin_bit_cast(bf16x8, w1);
    const bf16x8 pb2 = __builtin_bit_cast(bf16x8, w2);
    __builtin_amdgcn_s_setprio(1);
    ot0 = MFMA32x32x16(va[0][0], pb1, ot0);
    ot0 = MFMA32x32x16(va[0][1], pb2, ot0);
    ot1 = MFMA32x32x16(va[1][0], pb1, ot1);
    ot1 = MFMA32x32x16(va[1][1], pb2, ot1);
    __builtin_amdgcn_s_setprio(0);

    __builtin_amdgcn_sched_barrier(0);
    asm volatile("s_waitcnt lgkmcnt(0)" ::: "memory");
    __builtin_amdgcn_s_barrier();  // all waves done reading buf[cur] before overwrite
  }

  lsum += __shfl_xor(lsum, 32);  // merge the two half-row k-sets

  // epilogue: O^T regs -> per-wave LDS transpose -> coalesced store
  const float inv = 1.0f / lsum;
#pragma unroll
  for (int r = 0; r < 16; ++r) {
    const int ldr = (r & 3) + 8 * (r >> 2) + 4 * hb;
    etile[w][li][ldr] = (bf16)(ot0[r] * inv);
    etile[w][li][ldr + 32] = (bf16)(ot1[r] * inv);
  }
  asm volatile("s_waitcnt lgkmcnt(0)" ::: "memory");
  __builtin_amdgcn_sched_barrier(0);
  {
    bf16* op = out_lat + ((size_t)(boff + q0 + li)) * 1024 + h * 64 + hb * 32;
#pragma unroll
    for (int j = 0; j < 4; ++j)
      *(bf16x8*)(op + 8 * j) = *(const bf16x8*)&etile[w][li][hb * 32 + 8 * j];
  }
}

// ---------------- host launch ----------------
extern "C" void kernel_launch(void* const* d_in, const int* in_sizes, int n_in,
                              void* d_out, int out_size, void* d_ws, size_t ws_size,
                              hipStream_t stream) {
  const float* x   = (const float*)d_in[0];
  const float* w_c = (const float*)d_in[1];
  const float* w_k = (const float*)d_in[2];
  const float* w_v = (const float*)d_in[3];
  const float* w_q = (const float*)d_in[4];
  const float* w_o = (const float*)d_in[5];
  float* out = (float*)d_out;

  char* ws = (char*)d_ws;
  size_t off = 0;
  auto alloc = [&](size_t bytes) {
    char* p = ws + off;
    off += (bytes + 255) & ~(size_t)255;
    return p;
  };
  bf16* xb     = (bf16*)alloc((size_t)4096 * 1024 * 2);
  bf16* QLbuf  = (bf16*)alloc((size_t)4096 * 1088 * 2);  // q_lat | latent
  bf16* BTq    = (bf16*)alloc((size_t)1088 * 1024 * 2);  // W_qlatT ; w_c^T
  bf16* latT   = (bf16*)alloc((size_t)64 * 4096 * 2);
  bf16* outlat = (bf16*)alloc((size_t)4096 * 1024 * 2);
  bf16* WoutT  = (bf16*)alloc((size_t)1024 * 1024 * 2);

  // 1) all preprocessing in one dispatch
  prep_fused<<<4624, 256, 0, stream>>>(x, w_c, w_k, w_v, w_q, w_o, xb, BTq, WoutT);

  // 2) fused [q_lat | latent] = xb @ [W_qlatT ; w_c^T]^T : [4096][1088]
  gemm_bf16<128, 64, 2, 2, false><<<dim3(32, 17), 256, 0, stream>>>(
      xb, BTq, QLbuf, 1088, 1024);

  // 3) latT [64][4096] (k-permuted) from QLbuf latent columns
  make_latT<<<64, 256, 0, stream>>>(QLbuf, latT);

  // 4) attention: 512 blocks = (64 chunks x 2 b x 4 head-groups), 4 waves/block
  mla_attn5<<<512, 256, 0, stream>>>(QLbuf, latT, outlat);

  // 5) out = out_lat @ W_outT (fp32)
  gemm_bf16<64, 128, 1, 4, true><<<dim3(64, 8), 256, 0, stream>>>(
      outlat, WoutT, (void*)out, 1024, 1024);

  (void)in_sizes; (void)n_in; (void)out_size; (void)ws_size;
}